// Round 7
// baseline (15704.649 us; speedup 1.0000x reference)
//
#include <hip/hip_runtime.h>
#include <hip/hip_bf16.h>

// Problem constants
#define BATCH   64
#define SEQ     512
#define DMODEL  256
#define HIDDEN  512
#define G3      1536      // 3*HIDDEN
#define CHUNK   128       // timesteps per scan chunk-kernel
#define NCHUNK  4         // SEQ / CHUNK

// v14: 8 independent batch-groups, pipelined round-robin inside each block.
#define GROUPS  8
#define SPG     8                         // samples per group
#define NBLK    256                       // scan blocks; 2 units each
#define HSLOTG  (HIDDEN * SPG)            // 4096 floats per group h-slot (16 KB)
#define HGSTRIDE ((long)CHUNK * HSLOTG)   // floats per group's history (2 MB)

typedef unsigned long long u64;
typedef unsigned int u32;

// ---------------------------------------------------------------------------
// Pack Wh for v14: whp[(blk*6 + c)*512 + k] = Wh[k][gate*512 + blk*2 + uu],
// c = gate*2 + uu (blk 0..255 owns units blk*2, blk*2+1; 6 gate-cols).
// Consumed once per scan kernel into LDS.
// ---------------------------------------------------------------------------
__global__ __launch_bounds__(512) void prep_wh(const float* __restrict__ Wh,
                                               float* __restrict__ whp) {
    int t = blockIdx.x * 512 + threadIdx.x;      // 0 .. 786431
    int k  = t & 511;
    int cb = t >> 9;           // blk*6 + c, 0..1535
    int c   = cb % 6;
    int blk = cb / 6;
    int gate = c >> 1, uu = c & 1;
    whp[t] = Wh[(long)k * G3 + gate * HIDDEN + blk * 2 + uu];
}

// ---------------------------------------------------------------------------
// Zero the 256 per-block sweep flags (agent scope; monotonic global-step
// values across all 4 chunk kernels, initialized exactly once per launch).
// ---------------------------------------------------------------------------
__global__ void init_flags(unsigned* flags) {
    __hip_atomic_store(&flags[threadIdx.x], 0u, __ATOMIC_RELAXED,
                       __HIP_MEMORY_SCOPE_AGENT);
}

// ---------------------------------------------------------------------------
// Chunked xg GEMM: xgC[col][lt][b] = emb[ids[b][s]] . Wx[:,col] + bx[col].
// Unchanged from v8-v13.
// ---------------------------------------------------------------------------
__global__ __launch_bounds__(256) void xg_gemm(const int* __restrict__ ids,
                                               const float* __restrict__ emb,
                                               const float* __restrict__ Wx,
                                               const float* __restrict__ bx,
                                               float* __restrict__ xgC,
                                               int chunk) {
    __shared__ float Es[64][68];
    __shared__ float Ws[64][68];
    __shared__ int   sids[64];

    const int tid = threadIdx.x;
    const int nb = blockIdx.x;
    const int lt = blockIdx.y;
    const int s  = chunk * CHUNK + lt;
    const int tn = tid & 15;
    const int tm = tid >> 4;

    if (tid < 64) sids[tid] = ids[tid * SEQ + s];
    __syncthreads();

    float acc[4][4];
#pragma unroll
    for (int i = 0; i < 4; ++i)
#pragma unroll
        for (int j = 0; j < 4; ++j) acc[i][j] = 0.f;

    for (int kb = 0; kb < 256; kb += 64) {
#pragma unroll
        for (int p = 0; p < 4; ++p) {
            int b = p * 16 + tm;
            float4 av = *(const float4*)(emb + (long)sids[b] * DMODEL + kb + tn * 4);
            Es[tn * 4 + 0][b] = av.x;
            Es[tn * 4 + 1][b] = av.y;
            Es[tn * 4 + 2][b] = av.z;
            Es[tn * 4 + 3][b] = av.w;
            int krow = p * 16 + tm;
            float4 wv = *(const float4*)(Wx + (long)(kb + krow) * G3 + nb * 64 + tn * 4);
            *(float4*)&Ws[krow][tn * 4] = wv;
        }
        __syncthreads();
#pragma unroll
        for (int k = 0; k < 64; ++k) {
            float4 w4 = *(const float4*)&Ws[k][tm * 4];
            float4 e4 = *(const float4*)&Es[k][tn * 4];
            float ww[4] = {w4.x, w4.y, w4.z, w4.w};
            float ee[4] = {e4.x, e4.y, e4.z, e4.w};
#pragma unroll
            for (int i = 0; i < 4; ++i)
#pragma unroll
                for (int j = 0; j < 4; ++j)
                    acc[i][j] = fmaf(ww[i], ee[j], acc[i][j]);
        }
        __syncthreads();
    }

#pragma unroll
    for (int i = 0; i < 4; ++i) {
        int col = nb * 64 + tm * 4 + i;
        float bxi = bx[col];
        float4 o;
        o.x = acc[i][0] + bxi;
        o.y = acc[i][1] + bxi;
        o.z = acc[i][2] + bxi;
        o.w = acc[i][3] + bxi;
        *(float4*)(xgC + (long)col * (CHUNK * BATCH) + lt * 64 + tn * 4) = o;
    }
}

// ---------------------------------------------------------------------------
// GRU scan v14: 8 independent batch-groups pipelined through 256 one-wave
// blocks. v8-v12 proved a ~7us/step handoff floor that no protocol removes
// (agent ops always round-trip the MALL); v13 proved weights must not be
// per-lane-streamed from L2. v14 HIDES the handoff instead of shrinking it:
//  * h[t+1][b] depends only on h[t][b] -> samples split into 8 independent
//    groups of 8. Each block sweeps groups 0..7 per timestep; group g's
//    store->MALL->visibility latency is covered by 7 other groups' compute.
//  * block = 2 units x all 3 gates (6 cols) x 8 samples/group; ONE wave,
//    zero barriers, zero LDS hazards. lane = (s = ln&7, ks = ln>>3).
//  * weights: 12 KB slice in LDS, loaded ONCE per kernel (fixes v13);
//    [ks][c][64+pad4] layout -> ds_read_b128 2-way conflicts only (free).
//  * per-visit: fetch h[t][g] (16 coalesced float4/lane, double-buffered:
//    group g+1's fetch issues before group g's stores), 384 FMA, 3-stage
//    __shfl_xor reduce over ks, nonlin in-register (hprev lives in regs,
//    per-group arrays with fully-unrolled static indexing), 8-lane u64
//    h store (agent, write-through).
//  * sync ONCE PER SWEEP: lane0 release-stores flags[blk] = t+1 (release
//    = compiler-placed vmcnt drain covering all 8 groups' stores), and the
//    next sweep starts with one 256-flag poll (4 agent loads/lane).
//    flag >= t <=> every block finished sweep t-1 <=> h[t] all groups
//    complete. Skew <= 1 sweep << 128-slot reuse distance.
// Correctness: flags monotonic across chunks (init once; value = global
// step). Chunk carry: slot 0 = h[base] written by prev kernel (entry
// acquire); hprev regs reloaded from slot 0 at kernel start; chunk 0
// handles t==0 analytically (h0 = 0: no poll, no fetch, acc = 0).
// Deadlock-free: 256 one-wave blocks co-resident on 256 CUs; induction on
// sweeps.
// ---------------------------------------------------------------------------
__global__ __launch_bounds__(64) void gru_scan(const float* __restrict__ whp,
                                               const float* __restrict__ xgC,
                                               const float* __restrict__ bh,
                                               float* hist,
                                               unsigned* flags,
                                               int chunk) {
    const int ln  = threadIdx.x;
    const int blk = blockIdx.x;
    const int s   = ln & 7;        // sample within group
    const int ks  = ln >> 3;       // k-slice 0..7 (64 units each)
    const int u0  = blk * 2;
    const int u1  = blk * 2 + 1;

    __shared__ float wl[48 * 68];  // [ks][c][64 +4 pad] -> 13 KB

    // ---- preload weight slice into LDS (once per kernel) ----
#pragma unroll
    for (int p = 0; p < 48; ++p) {
        int c = p % 6, kss = p / 6;
        wl[p * 68 + ln] = whp[((long)blk * 6 + c) * 512 + kss * 64 + ln];
    }
    __syncthreads();               // single wave: drains LDS writes

    // biases for the 6 cols (c = gate*2 + uu)
    float bh0 = bh[u0], bh1 = bh[u1];
    float bh2 = bh[HIDDEN + u0], bh3 = bh[HIDDEN + u1];
    float bh4 = bh[2 * HIDDEN + u0], bh5 = bh[2 * HIDDEN + u1];

    const int base = chunk * CHUNK;

    // per-group hidden-state carry in registers (lane's sample s, units u0/u1)
    float hp0[GROUPS], hp1[GROUPS];
#pragma unroll
    for (int g = 0; g < GROUPS; ++g) {
        if (chunk == 0) { hp0[g] = 0.f; hp1[g] = 0.f; }
        else {
            hp0[g] = hist[(long)g * HGSTRIDE + (long)s * HIDDEN + u0];
            hp1[g] = hist[(long)g * HGSTRIDE + (long)s * HIDDEN + u1];
        }
    }

    float4 hA[16], hB[16];         // double-buffered h fetch (per-group 16 KB slot)

#define FETCH(DST, G) do {                                                      \
        const float4* _sp = (const float4*)(hist + ((long)(G) * CHUNK + lt) *   \
                            HSLOTG + (long)s * HIDDEN + ks * 64);               \
        _Pragma("unroll")                                                       \
        for (int j = 0; j < 16; ++j) DST[j] = _sp[j];                           \
    } while (0)

#define VISIT(G, CUR, NXT) do {                                                 \
        const int bb = (G) * SPG + s;                                           \
        float xr0 = xgC[(long)(u0)        * 8192 + lt * 64 + bb];               \
        float xr1 = xgC[(long)(u1)        * 8192 + lt * 64 + bb];               \
        float xz0 = xgC[(long)(512 + u0)  * 8192 + lt * 64 + bb];               \
        float xz1 = xgC[(long)(512 + u1)  * 8192 + lt * 64 + bb];               \
        float xn0 = xgC[(long)(1024 + u0) * 8192 + lt * 64 + bb];               \
        float xn1 = xgC[(long)(1024 + u1) * 8192 + lt * 64 + bb];               \
        float a0 = 0.f, a1 = 0.f, a2 = 0.f, a3 = 0.f, a4 = 0.f, a5 = 0.f;      \
        if (t > 0) {                                                            \
            _Pragma("unroll")                                                   \
            for (int j = 0; j < 16; ++j) {                                      \
                float4 hvj = CUR[j];                                            \
                float4 w;                                                       \
                w = *(const float4*)&wl[(ks * 6 + 0) * 68 + 4 * j];             \
                a0 = fmaf(hvj.x, w.x, a0); a0 = fmaf(hvj.y, w.y, a0);           \
                a0 = fmaf(hvj.z, w.z, a0); a0 = fmaf(hvj.w, w.w, a0);           \
                w = *(const float4*)&wl[(ks * 6 + 1) * 68 + 4 * j];             \
                a1 = fmaf(hvj.x, w.x, a1); a1 = fmaf(hvj.y, w.y, a1);           \
                a1 = fmaf(hvj.z, w.z, a1); a1 = fmaf(hvj.w, w.w, a1);           \
                w = *(const float4*)&wl[(ks * 6 + 2) * 68 + 4 * j];             \
                a2 = fmaf(hvj.x, w.x, a2); a2 = fmaf(hvj.y, w.y, a2);           \
                a2 = fmaf(hvj.z, w.z, a2); a2 = fmaf(hvj.w, w.w, a2);           \
                w = *(const float4*)&wl[(ks * 6 + 3) * 68 + 4 * j];             \
                a3 = fmaf(hvj.x, w.x, a3); a3 = fmaf(hvj.y, w.y, a3);           \
                a3 = fmaf(hvj.z, w.z, a3); a3 = fmaf(hvj.w, w.w, a3);           \
                w = *(const float4*)&wl[(ks * 6 + 4) * 68 + 4 * j];             \
                a4 = fmaf(hvj.x, w.x, a4); a4 = fmaf(hvj.y, w.y, a4);           \
                a4 = fmaf(hvj.z, w.z, a4); a4 = fmaf(hvj.w, w.w, a4);           \
                w = *(const float4*)&wl[(ks * 6 + 5) * 68 + 4 * j];             \
                a5 = fmaf(hvj.x, w.x, a5); a5 = fmaf(hvj.y, w.y, a5);           \
                a5 = fmaf(hvj.z, w.z, a5); a5 = fmaf(hvj.w, w.w, a5);           \
            }                                                                   \
        }                                                                       \
        if ((G) < 7 && t > 0) { FETCH(NXT, (G) + 1); }                          \
        a0 += __shfl_xor(a0, 8);  a0 += __shfl_xor(a0, 16); a0 += __shfl_xor(a0, 32); \
        a1 += __shfl_xor(a1, 8);  a1 += __shfl_xor(a1, 16); a1 += __shfl_xor(a1, 32); \
        a2 += __shfl_xor(a2, 8);  a2 += __shfl_xor(a2, 16); a2 += __shfl_xor(a2, 32); \
        a3 += __shfl_xor(a3, 8);  a3 += __shfl_xor(a3, 16); a3 += __shfl_xor(a3, 32); \
        a4 += __shfl_xor(a4, 8);  a4 += __shfl_xor(a4, 16); a4 += __shfl_xor(a4, 32); \
        a5 += __shfl_xor(a5, 8);  a5 += __shfl_xor(a5, 16); a5 += __shfl_xor(a5, 32); \
        float r0 = 1.f / (1.f + expf(-(xr0 + a0 + bh0)));                       \
        float r1 = 1.f / (1.f + expf(-(xr1 + a1 + bh1)));                       \
        float z0 = 1.f / (1.f + expf(-(xz0 + a2 + bh2)));                       \
        float z1 = 1.f / (1.f + expf(-(xz1 + a3 + bh3)));                       \
        float n0 = tanhf(xn0 + r0 * (a4 + bh4));                                \
        float n1 = tanhf(xn1 + r1 * (a5 + bh5));                                \
        float h0n = (1.f - z0) * n0 + z0 * hp0[(G)];                            \
        float h1n = (1.f - z1) * n1 + z1 * hp1[(G)];                            \
        hp0[(G)] = h0n; hp1[(G)] = h1n;                                         \
        if (ks == 0) {                                                          \
            u64 pk = ((u64)__float_as_uint(h1n) << 32) | (u64)__float_as_uint(h0n); \
            __hip_atomic_store((u64*)(hist + ((long)(G) * CHUNK + slot_w) *     \
                               HSLOTG + (long)s * HIDDEN + u0), pk,             \
                               __ATOMIC_RELAXED, __HIP_MEMORY_SCOPE_AGENT);     \
        }                                                                       \
    } while (0)

#pragma unroll 1
    for (int lt = 0; lt < CHUNK; ++lt) {
        const int t = base + lt;
        const int slot_w = (lt + 1) & (CHUNK - 1);

        if (t > 0) {
            // one poll per sweep: all 256 blocks finished sweep t-1
            const u32 tgt = (u32)t;
            for (;;) {
                u32 f0 = __hip_atomic_load(&flags[ln],       __ATOMIC_RELAXED, __HIP_MEMORY_SCOPE_AGENT);
                u32 f1 = __hip_atomic_load(&flags[64 + ln],  __ATOMIC_RELAXED, __HIP_MEMORY_SCOPE_AGENT);
                u32 f2 = __hip_atomic_load(&flags[128 + ln], __ATOMIC_RELAXED, __HIP_MEMORY_SCOPE_AGENT);
                u32 f3 = __hip_atomic_load(&flags[192 + ln], __ATOMIC_RELAXED, __HIP_MEMORY_SCOPE_AGENT);
                if (__all((int)(f0 >= tgt && f1 >= tgt && f2 >= tgt && f3 >= tgt))) break;
                __builtin_amdgcn_s_sleep(1);
            }
            asm volatile("" ::: "memory");   // no hoist of fetches above the poll
            FETCH(hA, 0);
        }

        VISIT(0, hA, hB);
        VISIT(1, hB, hA);
        VISIT(2, hA, hB);
        VISIT(3, hB, hA);
        VISIT(4, hA, hB);
        VISIT(5, hB, hA);
        VISIT(6, hA, hB);
        VISIT(7, hB, hA);

        // sweep complete: release-flag (compiler emits vmcnt drain of all
        // 8 groups' h stores before the store -> any post-poll reader is safe)
        if (ln == 0)
            __hip_atomic_store(&flags[blk], (u32)(t + 1),
                               __ATOMIC_RELEASE, __HIP_MEMORY_SCOPE_AGENT);
    }
#undef VISIT
#undef FETCH
}

// ---------------------------------------------------------------------------
// head: logits[b][n] = sum_k h[k] * Wo[k][n] + bo[n]
// Final h sits in each group's slot 0: hist[g][0][s][k].
// ---------------------------------------------------------------------------
__global__ void head_kernel(const float* __restrict__ hist,
                            const float* __restrict__ Wo,
                            const float* __restrict__ bo,
                            float* __restrict__ out) {
    int tid = threadIdx.x;        // 128 threads
    int b = tid >> 1, n = tid & 1;
    const float* hrow = hist + (long)(b >> 3) * HGSTRIDE + (long)(b & 7) * HIDDEN;
    float acc = bo[n];
#pragma unroll 8
    for (int k = 0; k < HIDDEN; ++k)
        acc = fmaf(hrow[k], Wo[k * 2 + n], acc);
    out[b * 2 + n] = acc;
}

// ---------------------------------------------------------------------------
extern "C" void kernel_launch(void* const* d_in, const int* in_sizes, int n_in,
                              void* d_out, int out_size, void* d_ws, size_t ws_size,
                              hipStream_t stream) {
    (void)in_sizes; (void)n_in; (void)out_size; (void)ws_size;
    const int*   ids = (const int*)  d_in[0];
    const float* emb = (const float*)d_in[1];
    const float* Wx  = (const float*)d_in[2];
    const float* Wh  = (const float*)d_in[3];
    const float* bx  = (const float*)d_in[4];
    const float* bh  = (const float*)d_in[5];
    const float* Wo  = (const float*)d_in[6];
    const float* bo  = (const float*)d_in[7];
    float* out = (float*)d_out;

    char* ws = (char*)d_ws;
    // ws layout: [flags 2KB][hist 16MB][whp 3MB][xgC 50.3MB]  (~70 MB total)
    // hist: 8 groups x 128 slots x (8 samples x 512 units). No init needed:
    // reads are flag-gated; chunk0/t0 is analytic.
    unsigned* flags = (unsigned*)ws;
    float* hist = (float*)(ws + 2048);
    float* whp  = (float*)(ws + 2048 + (size_t)GROUPS * HGSTRIDE * 4);
    float* xgC  = (float*)(ws + 2048 + (size_t)GROUPS * HGSTRIDE * 4
                           + (size_t)NBLK * 6 * HIDDEN * 4);

    init_flags<<<dim3(1), dim3(256), 0, stream>>>(flags);
    prep_wh<<<dim3(1536), dim3(512), 0, stream>>>(Wh, whp);
    for (int c = 0; c < NCHUNK; ++c) {
        xg_gemm<<<dim3(24, CHUNK), dim3(256), 0, stream>>>(ids, emb, Wx, bx, xgC, c);
        gru_scan<<<dim3(NBLK), dim3(64), 0, stream>>>(whp, xgC, bh, hist, flags, c);
    }
    head_kernel<<<dim3(1), dim3(128), 0, stream>>>(hist, Wo, bo, out);
}

// Round 8
// 4942.001 us; speedup vs baseline: 3.1778x; 3.1778x over previous
//
#include <hip/hip_runtime.h>
#include <hip/hip_bf16.h>

// Problem constants
#define BATCH   64
#define SEQ     512
#define DMODEL  256
#define HIDDEN  512
#define G3      1536      // 3*HIDDEN
#define NBLK    128       // scan blocks; 512 hidden units / 128 = 4 units/block
#define UPB     4         // units per block
#define CPB     12        // Wh columns per block (3 gates * UPB)
#define CHUNK   128       // timesteps per scan chunk-kernel
#define NCHUNK  4         // SEQ / CHUNK
#define HSLOT   (HIDDEN * BATCH)   // floats per h slot (128 KB)

// Sentinel: negative quiet NaN bit pattern. Real h = (1-z)*n + z*h_prev with
// n in (-1,1), z in (0,1), h0=0  =>  h strictly in (-1,1), never NaN/inf.
#define SENT32  0xFFC00000u
#define SENT64  0xFFC00000FFC00000ULL

typedef unsigned long long u64;
typedef unsigned int u32;

// ---------------------------------------------------------------------------
// Pack Wh slices: whp[blk][c][k] = Wh[k][ g*512 + blk*4 + u ]  (c = g*4+u)
// Contiguous in k -> wave-uniform weight reads scalarize (s_load). With no
// invalidation anywhere in the scan loop, each block's 24 KB slice stays
// L2-hot for the whole chunk.
// ---------------------------------------------------------------------------
__global__ __launch_bounds__(512) void prep_wh(const float* __restrict__ Wh,
                                               float* __restrict__ whp) {
    int t = blockIdx.x * 512 + threadIdx.x;      // 0 .. 786431
    int k   = t & 511;
    int cb  = t >> 9;          // blk*12 + c
    int c   = cb % 12;
    int blk = cb / 12;
    int u = c & 3, g = c >> 2;
    whp[t] = Wh[(long)k * G3 + g * HIDDEN + blk * UPB + u];
}

// ---------------------------------------------------------------------------
// Chunked xg GEMM + folded sentinel clear.
// xgC[col][lt][b] = emb[ids[b][s]] . Wx[:,col] + bx[col], s = chunk*CHUNK+lt.
// Clear fold: before the GEMM, the 3072 blocks cooperatively sentinel-fill
// hist slots 1..127 (2,080,768 u64) with PLAIN write-back stores (~5 KB per
// block, overlapped with GEMM compute). Kernel-exit release pushes dirty L2
// to the MALL -- the same mechanism that has made xgC (plain stores, plain
// consumer loads) coherent across kernel boundaries since v8 -- so the
// scan's agent-scope (MALL-direct) data-polls observe the sentinels.
// This deletes v10's 4 hist_clear dispatches (launch + ~30-40us each).
// ---------------------------------------------------------------------------
__global__ __launch_bounds__(256) void xg_gemm(const int* __restrict__ ids,
                                               const float* __restrict__ emb,
                                               const float* __restrict__ Wx,
                                               const float* __restrict__ bx,
                                               float* __restrict__ xgC,
                                               float* __restrict__ hist,
                                               int chunk) {
    __shared__ float Es[64][68];   // Es[k][b], padded
    __shared__ float Ws[64][68];   // Ws[k][c], padded
    __shared__ int   sids[64];

    const int tid = threadIdx.x;
    const int nb = blockIdx.x;     // col tile 0..23
    const int lt = blockIdx.y;     // local timestep 0..127
    const int s  = chunk * CHUNK + lt;
    const int tn = tid & 15;
    const int tm = tid >> 4;

    // ---- folded sentinel clear of hist slots 1..127 ----
    {
        long gid = ((long)(blockIdx.y * 24 + blockIdx.x)) * 256 + tid; // 0..786431
        u64* hq = (u64*)(hist + HSLOT);
#pragma unroll
        for (int r = 0; r < 3; ++r) {
            long i = gid + (long)r * 786432;
            if (i < 2080768) hq[i] = SENT64;
        }
    }

    if (tid < 64) sids[tid] = ids[tid * SEQ + s];   // id for batch=tid, step s
    __syncthreads();

    float acc[4][4];               // acc[i=col][j=b]
#pragma unroll
    for (int i = 0; i < 4; ++i)
#pragma unroll
        for (int j = 0; j < 4; ++j) acc[i][j] = 0.f;

    for (int kb = 0; kb < 256; kb += 64) {
#pragma unroll
        for (int p = 0; p < 4; ++p) {
            int b = p * 16 + tm;
            float4 av = *(const float4*)(emb + (long)sids[b] * DMODEL + kb + tn * 4);
            Es[tn * 4 + 0][b] = av.x;
            Es[tn * 4 + 1][b] = av.y;
            Es[tn * 4 + 2][b] = av.z;
            Es[tn * 4 + 3][b] = av.w;
            int krow = p * 16 + tm;
            float4 wv = *(const float4*)(Wx + (long)(kb + krow) * G3 + nb * 64 + tn * 4);
            *(float4*)&Ws[krow][tn * 4] = wv;
        }
        __syncthreads();
#pragma unroll
        for (int k = 0; k < 64; ++k) {
            float4 w4 = *(const float4*)&Ws[k][tm * 4];
            float4 e4 = *(const float4*)&Es[k][tn * 4];
            float ww[4] = {w4.x, w4.y, w4.z, w4.w};
            float ee[4] = {e4.x, e4.y, e4.z, e4.w};
#pragma unroll
            for (int i = 0; i < 4; ++i)
#pragma unroll
                for (int j = 0; j < 4; ++j)
                    acc[i][j] = fmaf(ww[i], ee[j], acc[i][j]);
        }
        __syncthreads();
    }

#pragma unroll
    for (int i = 0; i < 4; ++i) {
        int col = nb * 64 + tm * 4 + i;
        float bxi = bx[col];
        float4 o;
        o.x = acc[i][0] + bxi;
        o.y = acc[i][1] + bxi;
        o.z = acc[i][2] + bxi;
        o.w = acc[i][3] + bxi;
        *(float4*)(xgC + (long)col * (CHUNK * BATCH) + lt * 64 + tn * 4) = o;
    }
}

// ---------------------------------------------------------------------------
// GRU scan v15 == v10 (the measured champion, 8.9us/step): the data IS the
// flag. Protocol ablation v8-v14: four-barrier chain (v8), per-unit flags +
// fused loads (v9), flags + register-resident agent reads (v11), flags +
// plain L2 reads (v12), XCD batch-groups (v13), group pipelining (v14) --
// ALL lose to this form. Its legs:
//  * h slots 1..127 pre-filled with NaN sentinel (0xFFC00000) by the clear
//    fold in xg_gemm. Real h is strictly in (-1,1): no false positive.
//  * producer: computes h, issues ONE agent-scope write-through store.
//    No drain, no flag (drain+flag measured +0.7us/step in v11).
//  * consumer wave: polls the h DATA itself -- 64 agent-scope (MALL-direct)
//    dword loads per iteration + non-sentinel check. The validity check
//    forces all 64 values live in VGPRs (VGPR~120), so loads issue fully
//    parallel and on detection the values are ALREADY in registers: the
//    detect and fetch legs are ONE round trip.
// Correctness:
//  * 4B stores are atomic: a poll sees either sentinel or the final value.
//  * skew bound: a block cannot pass step t's poll until every block
//    finished step t-1 => max skew 1 step << 128-slot reuse distance.
//  * agent-scope loads observe write-through stores at the MALL (proven
//    v8-v12); sentinel writes arrive via xg_gemm's exit release.
//  * chunk carry: slot 0 is never cleared, written by prev chunk's last
//    step, read at lt=0 (poll exits on first iteration) and as hprev.
//    Chunk 0 skips step 0 analytically (h0 = 0).
// Deadlock-free: 128 blocks co-resident (<=256 CUs, one kernel at a time);
// forward progress by induction on t.
// ---------------------------------------------------------------------------
__global__ __launch_bounds__(512, 2) void gru_scan(const float* __restrict__ whp,
                                                   const float* __restrict__ xgC,
                                                   const float* __restrict__ bh,
                                                   float* hist,
                                                   int chunk) {
    const int tid = threadIdx.x;
    const int blk = blockIdx.x;
    const int b   = tid & 63;                                 // lane = batch
    const int wu  = __builtin_amdgcn_readfirstlane(tid >> 6); // wave 0..7

    __shared__ float part[2][8][CPB][64];   // 48 KB double-buffered partials

    const float* wb = whp + blk * (CPB * HIDDEN) + wu * 64;   // + c*512 + k
    const int base = chunk * CHUNK;

    // producer-wave state (waves 0-3 own unit jg = blk*4 + wu)
    int jg = 0;
    float bhr = 0.f, bhz = 0.f, bhn = 0.f, hprev = 0.f;
    const float* xr_p = nullptr; const float* xz_p = nullptr; const float* xn_p = nullptr;
    if (wu < 4) {
        jg  = blk * UPB + wu;
        bhr = bh[jg];
        bhz = bh[HIDDEN + jg];
        bhn = bh[2 * HIDDEN + jg];
        xr_p = xgC + (long)jg * (CHUNK * BATCH) + b;
        xz_p = xgC + (long)(HIDDEN + jg) * (CHUNK * BATCH) + b;
        xn_p = xgC + (long)(2 * HIDDEN + jg) * (CHUNK * BATCH) + b;
        // slot 0 holds h[base] (written by previous chunk kernel; fresh via
        // kernel-entry acquire). Chunk 0: h0 = 0.
        hprev = (chunk == 0) ? 0.f : hist[(long)jg * 64 + b];
    }

#pragma unroll 1
    for (int lt = 0; lt < CHUNK; ++lt) {
        const int t  = base + lt;
        const int pb = lt & 1;
        // this wave's 64 source units of h[t]: units wu*64 .. wu*64+63, batch b
        const u32* hq = (const u32*)(hist + (long)lt * HSLOT) + wu * (64 * 64) + b;
        float*     hw = hist + (long)((lt + 1) & (CHUNK - 1)) * HSLOT;   // h[t+1]

        // gate inputs: plain cached loads, issued before the poll so the
        // (possibly cold) fetch overlaps the wait.
        float xr = 0.f, xz = 0.f, xn = 0.f;
        if (wu < 4) {
            xr = xr_p[lt * 64];
            xz = xz_p[lt * 64];
            xn = xn_p[lt * 64];
        }

        float acc[CPB];
#pragma unroll
        for (int c = 0; c < CPB; ++c) acc[c] = 0.f;

        if (t > 0) {
            // poll the data: 64 parallel bypass loads + sentinel check.
            float hv[64];
            for (;;) {
                int valid = 1;
#pragma unroll
                for (int i = 0; i < 64; ++i) {
                    u32 w = __hip_atomic_load(hq + i * 64, __ATOMIC_RELAXED,
                                              __HIP_MEMORY_SCOPE_AGENT);
                    hv[i] = __uint_as_float(w);
                    valid &= (w != SENT32);
                }
                if (__all(valid)) break;
                // no sleep: each iteration self-throttles on memory latency
            }
#pragma unroll
            for (int i = 0; i < 64; ++i) {
                const float hvv = hv[i];
#pragma unroll
                for (int c = 0; c < CPB; ++c)
                    acc[c] = fmaf(hvv, wb[c * HIDDEN + i], acc[c]);
            }
        }
        // else: h0 == 0 => partials are 0, hg = bh (analytic first step)

#pragma unroll
        for (int c = 0; c < CPB; ++c) part[pb][wu][c][b] = acc[c];
        __syncthreads();               // the ONLY barrier per step

        if (wu < 4) {
            __builtin_amdgcn_s_setprio(1);
            float hgr = bhr, hgz = bhz, hgn = bhn;
#pragma unroll
            for (int ww = 0; ww < 8; ++ww) {
                hgr += part[pb][ww][wu][b];
                hgz += part[pb][ww][4 + wu][b];
                hgn += part[pb][ww][8 + wu][b];
            }
            float r  = 1.f / (1.f + expf(-(xr + hgr)));
            float z  = 1.f / (1.f + expf(-(xz + hgz)));
            float nn = tanhf(xn + r * hgn);
            float hnew = (1.f - z) * nn + z * hprev;
            hprev = hnew;
            // publish: ONE write-through store; consumers validate the data.
            __hip_atomic_store((u32*)hw + (long)jg * 64 + b, __float_as_uint(hnew),
                               __ATOMIC_RELAXED, __HIP_MEMORY_SCOPE_AGENT);
            __builtin_amdgcn_s_setprio(0);
        }
        // waves 4-7 proceed straight to step t+1's poll; their part writes
        // target buffer (pb^1), which waves 0-3 are not reading.
    }
}

// ---------------------------------------------------------------------------
// head: logits[b][n] = sum_k h[k][b] * Wo[k][n] + bo[n]
// h[512] sits in hist slot 0 (written by chunk 3's last step), [u][b] layout.
// ---------------------------------------------------------------------------
__global__ void head_kernel(const float* __restrict__ hist,
                            const float* __restrict__ Wo,
                            const float* __restrict__ bo,
                            float* __restrict__ out) {
    int tid = threadIdx.x;        // 128 threads
    int b = tid >> 1, n = tid & 1;
    float acc = bo[n];
#pragma unroll 8
    for (int k = 0; k < HIDDEN; ++k)
        acc = fmaf(hist[(long)k * 64 + b], Wo[k * 2 + n], acc);
    out[b * 2 + n] = acc;
}

// ---------------------------------------------------------------------------
extern "C" void kernel_launch(void* const* d_in, const int* in_sizes, int n_in,
                              void* d_out, int out_size, void* d_ws, size_t ws_size,
                              hipStream_t stream) {
    (void)in_sizes; (void)n_in; (void)out_size; (void)ws_size;
    const int*   ids = (const int*)  d_in[0];
    const float* emb = (const float*)d_in[1];
    const float* Wx  = (const float*)d_in[2];
    const float* Wh  = (const float*)d_in[3];
    const float* bx  = (const float*)d_in[4];
    const float* bh  = (const float*)d_in[5];
    const float* Wo  = (const float*)d_in[6];
    const float* bo  = (const float*)d_in[7];
    float* out = (float*)d_out;

    char* ws = (char*)d_ws;
    // ws layout: [hist 16MB][whp 3MB][xgC 50.3MB]  (~70 MB total)
    // hist slots 1..127 are sentinel-cleared inside each chunk's xg_gemm;
    // slot 0 is the cross-chunk carry (written before read in every kernel).
    float* hist = (float*)ws;
    float* whp  = (float*)(ws + (size_t)CHUNK * HSLOT * 4);
    float* xgC  = (float*)(ws + (size_t)CHUNK * HSLOT * 4
                           + (size_t)NBLK * CPB * HIDDEN * 4);

    prep_wh<<<dim3(1536), dim3(512), 0, stream>>>(Wh, whp);
    for (int c = 0; c < NCHUNK; ++c) {
        xg_gemm<<<dim3(24, CHUNK), dim3(256), 0, stream>>>(ids, emb, Wx, bx, xgC, hist, c);
        gru_scan<<<dim3(NBLK), dim3(512), 0, stream>>>(whp, xgC, bh, hist, c);
    }
    head_kernel<<<dim3(1), dim3(128), 0, stream>>>(hist, Wo, bo, out);
}